// Round 9
// baseline (170.466 us; speedup 1.0000x reference)
//
#include <hip/hip_runtime.h>
#include <hip/hip_bf16.h>
#include <cmath>

#define B_   2
#define S_   2048
#define D_   768
#define H_   12
#define HD_  64
#define WIN_ 64

typedef __bf16 bf16x8 __attribute__((ext_vector_type(8)));
typedef __bf16 bf16x4 __attribute__((ext_vector_type(4)));
typedef float  f32x4  __attribute__((ext_vector_type(4)));
typedef unsigned int u32;

__device__ __forceinline__ void async_ld16(const void* g, void* l) {
    __builtin_amdgcn_global_load_lds(
        (__attribute__((address_space(1))) void*)(size_t)g,
        (__attribute__((address_space(3))) void*)(u32)(size_t)l,
        16, 0, 0);
}

#define WAIT_VM0   0x0F70   // vmcnt(0), lgkm/exp no-wait
#define WAIT_LGKM0 0xC07F   // lgkmcnt(0), vm/exp no-wait

__device__ __forceinline__ bf16x8 pack8(f32x4 a, f32x4 b) {
    bf16x8 r = { (__bf16)a[0], (__bf16)a[1], (__bf16)a[2], (__bf16)a[3],
                 (__bf16)b[0], (__bf16)b[1], (__bf16)b[2], (__bf16)b[3] };
    return r;
}

// ---------------------------------------------------------------------------
// Split-K GEMM, fp32-or-bf16 operands staged via global_load_lds, bf16 MFMA.
// C[M,N] = A[M,K] * Bw[N,K]^T, 64x64 tile per block, SPLIT waves split K.
// fp32 rows (128 B = 8x16B chunks) stored rotated by row (chunk' = (c+row)&7)
// so frag ds_read_b128 is 2-way bank-aliased (free); bf16 rows (4 chunks)
// rotated by row&3.  Staging stays fully coalesced (permute within a row).
// Epilogues bounce through LDS for full-line coalesced stores (the 2-B/8-B
// scatter stores caused 3x write-allocate overfetch in rounds 5-8).
// MODE 0: fp32 C.  MODE 1: fused RoPE -> qkv bf16 (n<1536); v -> vt bf16^T.
// ---------------------------------------------------------------------------
template <int MODE, int SPLIT, int AF32, int BF32>
__global__ __launch_bounds__(64 * SPLIT) void gemm_f(
        const void* __restrict__ Av, const void* __restrict__ Bv,
        float* __restrict__ C, __bf16* __restrict__ qkv, __bf16* __restrict__ vt,
        const int* __restrict__ pos, int M, int N, int K) {
    constexpr int ABYTES = AF32 ? 8192 : 4096;
    constexpr int BBYTES = BF32 ? 8192 : 4096;
    constexpr int WBYTES = ABYTES + BBYTES;
    __shared__ __attribute__((aligned(16))) char smem[SPLIT * WBYTES];

    const int tid = threadIdx.x;
    const int w = tid >> 6, lane = tid & 63;
    const int m0 = blockIdx.y * 64;
    const int n0 = blockIdx.x * 64;
    const int fr = lane & 15, fq = lane >> 4;

    char* As = smem + w * WBYTES;
    char* Bs = As + ABYTES;

    f32x4 acc[4][4] = {};
    const int nkw = (K / SPLIT) >> 5;
    const int kbase = w * (K / SPLIT);

    for (int ki = 0; ki < nkw; ++ki) {
        const int k0 = kbase + (ki << 5);
        __builtin_amdgcn_s_waitcnt(WAIT_LGKM0);   // prior frag reads retired
        // ---- stage A ----
        if (AF32) {
            const float* Af = (const float*)Av;
            #pragma unroll
            for (int i = 0; i < 8; ++i) {
                int c = i * 64 + lane, row = c >> 3, ch = c & 7;
                int cc = (ch - row) & 7;
                async_ld16(Af + (size_t)(m0 + row) * K + k0 + cc * 4, As + c * 16);
            }
        } else {
            const __bf16* Ab = (const __bf16*)Av;
            #pragma unroll
            for (int i = 0; i < 4; ++i) {
                int c = i * 64 + lane, row = c >> 2, ch = c & 3;
                int cc = (ch - row) & 3;
                async_ld16(Ab + (size_t)(m0 + row) * K + k0 + cc * 8, As + c * 16);
            }
        }
        // ---- stage B ----
        if (BF32) {
            const float* Bf = (const float*)Bv;
            #pragma unroll
            for (int i = 0; i < 8; ++i) {
                int c = i * 64 + lane, row = c >> 3, ch = c & 7;
                int cc = (ch - row) & 7;
                async_ld16(Bf + (size_t)(n0 + row) * K + k0 + cc * 4, Bs + c * 16);
            }
        } else {
            const __bf16* Bb = (const __bf16*)Bv;
            #pragma unroll
            for (int i = 0; i < 4; ++i) {
                int c = i * 64 + lane, row = c >> 2, ch = c & 3;
                int cc = (ch - row) & 3;
                async_ld16(Bb + (size_t)(n0 + row) * K + k0 + cc * 8, Bs + c * 16);
            }
        }
        __builtin_amdgcn_s_waitcnt(WAIT_VM0);

        bf16x8 af[4], bfv[4];
        #pragma unroll
        for (int t = 0; t < 4; ++t) {
            const int row = t * 16 + fr;
            if (AF32) {
                const float* rA = (const float*)As + row * 32;
                const int p0 = (2 * fq + row) & 7, p1 = (p0 + 1) & 7;
                af[t] = pack8(*(const f32x4*)(rA + p0 * 4), *(const f32x4*)(rA + p1 * 4));
            } else {
                const __bf16* rA = (const __bf16*)As + row * 32;
                af[t] = *(const bf16x8*)(rA + ((fq + row) & 3) * 8);
            }
            if (BF32) {
                const float* rB = (const float*)Bs + row * 32;
                const int p0 = (2 * fq + row) & 7, p1 = (p0 + 1) & 7;
                bfv[t] = pack8(*(const f32x4*)(rB + p0 * 4), *(const f32x4*)(rB + p1 * 4));
            } else {
                const __bf16* rB = (const __bf16*)Bs + row * 32;
                bfv[t] = *(const bf16x8*)(rB + ((fq + row) & 3) * 8);
            }
        }
        #pragma unroll
        for (int ti = 0; ti < 4; ++ti)
            #pragma unroll
            for (int tj = 0; tj < 4; ++tj)
                acc[ti][tj] = __builtin_amdgcn_mfma_f32_16x16x32_bf16(
                    af[ti], bfv[tj], acc[ti][tj], 0, 0, 0);
    }

    // ---- serial lane-aligned reduction into wave 0 ----
    float* red = (float*)(smem + SPLIT * WBYTES - 16384);
    __syncthreads();
    #pragma unroll
    for (int src = 1; src < SPLIT; ++src) {
        if (w == src) {
            #pragma unroll
            for (int ti = 0; ti < 4; ++ti)
                #pragma unroll
                for (int tj = 0; tj < 4; ++tj)
                    *(f32x4*)(red + (ti * 4 + tj) * 256 + lane * 4) = acc[ti][tj];
        }
        __syncthreads();
        if (w == 0) {
            #pragma unroll
            for (int ti = 0; ti < 4; ++ti)
                #pragma unroll
                for (int tj = 0; tj < 4; ++tj)
                    acc[ti][tj] += *(const f32x4*)(red + (ti * 4 + tj) * 256 + lane * 4);
        }
        __syncthreads();
    }
    if (w != 0) return;

    // ---- wave-0 epilogue, coalesced via LDS bounce ----
    if (MODE == 0) {
        float* eL = (float*)smem;                 // [64][65] fp32, 16.6 KB
        #pragma unroll
        for (int ti = 0; ti < 4; ++ti)
            #pragma unroll
            for (int tj = 0; tj < 4; ++tj)
                #pragma unroll
                for (int r = 0; r < 4; ++r)
                    eL[(ti * 16 + fq * 4 + r) * 65 + tj * 16 + fr] = acc[ti][tj][r];
        #pragma unroll
        for (int p = 0; p < 16; ++p) {
            const int rc = p * 4 + (lane >> 4), ch = lane & 15;
            f32x4 vv = *(const f32x4*)(eL + rc * 65 + ch * 4);
            *(f32x4*)(C + (size_t)(m0 + rc) * N + n0 + ch * 4) = vv;
        }
    } else if (n0 < 2 * D_) {
        // fused RoPE on fp32 acc, then bf16 coalesced store
        const float invf0 = __powf(10000.0f, -(float)fr * (1.0f / 32.0f));
        const float invf1 = __powf(10000.0f, -(float)(16 + fr) * (1.0f / 32.0f));
        #pragma unroll
        for (int ti = 0; ti < 4; ++ti)
            #pragma unroll
            for (int r = 0; r < 4; ++r) {
                const int row = m0 + ti * 16 + fq * 4 + r;
                const float p = (float)pos[row];
                float s0, c0, s1, c1;
                __sincosf(p * invf0, &s0, &c0);
                __sincosf(p * invf1, &s1, &c1);
                const float x0 = acc[ti][0][r], x1 = acc[ti][2][r];
                acc[ti][0][r] = x0 * c0 - x1 * s0;
                acc[ti][2][r] = x1 * c0 + x0 * s0;
                const float y0 = acc[ti][1][r], y1 = acc[ti][3][r];
                acc[ti][1][r] = y0 * c1 - y1 * s1;
                acc[ti][3][r] = y1 * c1 + y0 * s1;
            }
        __bf16* eL = (__bf16*)smem;               // [64][68] bf16, 8.7 KB
        #pragma unroll
        for (int ti = 0; ti < 4; ++ti)
            #pragma unroll
            for (int tj = 0; tj < 4; ++tj)
                #pragma unroll
                for (int r = 0; r < 4; ++r)
                    eL[(ti * 16 + fq * 4 + r) * 68 + tj * 16 + fr] = (__bf16)acc[ti][tj][r];
        #pragma unroll
        for (int p = 0; p < 8; ++p) {
            const int rq = p * 8 + (lane >> 3), ch = lane & 7;
            bf16x8 vv = *(const bf16x8*)(eL + rq * 68 + ch * 8);
            *(bf16x8*)(qkv + (size_t)(m0 + rq) * (2 * D_) + n0 + ch * 8) = vv;
        }
    } else {
        // v -> vt[b][h][d][token], transposed in LDS, coalesced 128-B rows
        const int h = (n0 - 2 * D_) >> 6;
        const int bb = m0 >> 11, t0 = m0 & (S_ - 1);
        __bf16* eL = (__bf16*)smem;               // [64 d][68 tok] bf16
        #pragma unroll
        for (int ti = 0; ti < 4; ++ti)
            #pragma unroll
            for (int tj = 0; tj < 4; ++tj)
                #pragma unroll
                for (int r = 0; r < 4; ++r)
                    eL[(tj * 16 + fr) * 68 + ti * 16 + fq * 4 + r] = (__bf16)acc[ti][tj][r];
        const size_t vb = (size_t)((bb * H_ + h) * HD_) * S_ + t0;
        #pragma unroll
        for (int p = 0; p < 8; ++p) {
            const int d = p * 8 + (lane >> 3), ch = lane & 7;
            bf16x8 vv = *(const bf16x8*)(eL + d * 68 + ch * 8);
            *(bf16x8*)(vt + vb + (size_t)d * S_ + ch * 8) = vv;
        }
    }
}

// ---------------------------------------------------------------------------
// MFMA banded attention.  Block = 64 queries x (head, batch), 4 waves.
// LDS (48 KB): Ks [2][192][32] (24 KB, overlaid by P), Vts [6][64][32] (24 KB).
// Q frags direct from global.  O store bounced through LDS (coalesced 128-B).
// ---------------------------------------------------------------------------
__global__ __launch_bounds__(256) void attn_mfma(const __bf16* __restrict__ qkv,
                                                 const __bf16* __restrict__ vt,
                                                 __bf16* __restrict__ outb) {
    __shared__ __attribute__((aligned(16))) __bf16 smem[24576];  // 48 KB
    __bf16* Ks  = smem;
    __bf16* Vts = smem + 12288;

    const int i0  = blockIdx.x * 64;
    const int h   = blockIdx.y;
    const int b   = blockIdx.z;
    const int tid = threadIdx.x;
    const int w = tid >> 6, lane = tid & 63;
    const int fr = lane & 15, fq = lane >> 4;
    const int wq0 = w * 16;

    #pragma unroll
    for (int i = 0; i < 6; ++i) {
        int c = i * 256 + tid;
        int ks = (i >= 3);
        int rem = c - ks * 768;
        int cc = rem & 3, row = rem >> 2;
        int j = i0 - 64 + row; j = min(max(j, 0), S_ - 1);   // clamped; masked later
        async_ld16(qkv + ((size_t)b * S_ + j) * (2 * D_) + D_ + h * HD_ + ks * 32 + cc * 8,
                   Ks + c * 8);
    }
    const size_t vbase = (size_t)((b * H_ + h) * HD_) * S_;
    #pragma unroll
    for (int i = 0; i < 6; ++i) {
        int c = i * 256 + tid;
        int ks = c >> 8, rem = c & 255, d = rem >> 2, cc = rem & 3;
        int key = i0 - 64 + ks * 32 + cc * 8;
        key = min(max(key, 0), S_ - 8);                      // clamped; masked later
        async_ld16(vt + vbase + (size_t)d * S_ + key, Vts + c * 8);
    }

    const size_t qrow = ((size_t)b * S_ + i0 + wq0 + fr) * (2 * D_) + h * HD_;
    bf16x8 aq[2];
    aq[0] = *(const bf16x8*)(qkv + qrow + fq * 8);
    aq[1] = *(const bf16x8*)(qkv + qrow + 32 + fq * 8);

    __syncthreads();

    f32x4 sc[12] = {};
    #pragma unroll
    for (int nt = 0; nt < 12; ++nt) {
        #pragma unroll
        for (int ks = 0; ks < 2; ++ks) {
            bf16x8 bk = *(const bf16x8*)(Ks + (ks * 192 + nt * 16 + fr) * 32 + fq * 8);
            sc[nt] = __builtin_amdgcn_mfma_f32_16x16x32_bf16(aq[ks], bk, sc[nt], 0, 0, 0);
        }
    }

    float mx[4] = { -1e30f, -1e30f, -1e30f, -1e30f };
    #pragma unroll
    for (int nt = 0; nt < 12; ++nt) {
        const int jr = nt * 16 + fr;
        const int j  = i0 - 64 + jr;
        const bool jv = (j >= 0) && (j < S_);
        #pragma unroll
        for (int r = 0; r < 4; ++r) {
            const int ir = wq0 + fq * 4 + r + 64;
            const int dd = ir - jr;
            const bool v = jv && (dd <= WIN_) && (dd >= -WIN_);
            sc[nt][r] = v ? sc[nt][r] * 0.125f : -1e30f;
            mx[r] = fmaxf(mx[r], sc[nt][r]);
        }
    }
    #pragma unroll
    for (int r = 0; r < 4; ++r)
        #pragma unroll
        for (int off = 1; off < 16; off <<= 1)
            mx[r] = fmaxf(mx[r], __shfl_xor(mx[r], off, 64));

    float sm[4] = { 0.f, 0.f, 0.f, 0.f };
    #pragma unroll
    for (int nt = 0; nt < 12; ++nt)
        #pragma unroll
        for (int r = 0; r < 4; ++r) {
            float e = __expf(sc[nt][r] - mx[r]);
            sc[nt][r] = e;
            sm[r] += e;
        }
    #pragma unroll
    for (int r = 0; r < 4; ++r) {
        #pragma unroll
        for (int off = 1; off < 16; off <<= 1)
            sm[r] += __shfl_xor(sm[r], off, 64);
        sm[r] = 1.0f / sm[r];
    }

    __syncthreads();

    __bf16* Pw = Ks + w * 3072;
    #pragma unroll
    for (int nt = 0; nt < 12; ++nt) {
        const int ks = nt >> 1, kk = (nt & 1) * 16 + fr;
        #pragma unroll
        for (int r = 0; r < 4; ++r)
            Pw[(ks * 16 + fq * 4 + r) * 32 + kk] = (__bf16)(sc[nt][r] * sm[r]);
    }

    f32x4 oacc[4] = {};
    #pragma unroll
    for (int ks = 0; ks < 6; ++ks) {
        bf16x8 ap = *(const bf16x8*)(Pw + (ks * 16 + fr) * 32 + fq * 8);
        #pragma unroll
        for (int nt2 = 0; nt2 < 4; ++nt2) {
            bf16x8 bv = *(const bf16x8*)(Vts + (ks * 64 + nt2 * 16 + fr) * 32 + fq * 8);
            oacc[nt2] = __builtin_amdgcn_mfma_f32_16x16x32_bf16(ap, bv, oacc[nt2], 0, 0, 0);
        }
    }

    // O via per-wave LDS bounce (reuse Pw region) -> coalesced 128-B rows
    #pragma unroll
    for (int nt2 = 0; nt2 < 4; ++nt2)
        #pragma unroll
        for (int r = 0; r < 4; ++r)
            Pw[(fq * 4 + r) * 68 + nt2 * 16 + fr] = (__bf16)oacc[nt2][r];
    #pragma unroll
    for (int p = 0; p < 2; ++p) {
        const int q = p * 8 + (lane >> 3), ch = lane & 7;
        bf16x8 vv = *(const bf16x8*)(Pw + q * 68 + ch * 8);
        *(bf16x8*)(outb + ((size_t)b * S_ + i0 + wq0 + q) * D_ + h * HD_ + ch * 8) = vv;
    }
}

// ---------------------------------------------------------------------------
extern "C" void kernel_launch(void* const* d_in, const int* in_sizes, int n_in,
                              void* d_out, int out_size, void* d_ws, size_t ws_size,
                              hipStream_t stream) {
    const float* hs   = (const float*)d_in[0];
    const float* wqkv = (const float*)d_in[1];
    const float* wo   = (const float*)d_in[2];
    const int*   pos  = (const int*)d_in[4];
    float* out = (float*)d_out;

    __bf16* qkv     = (__bf16*)d_ws;                          // 4096*1536
    __bf16* vt      = qkv + (size_t)(B_ * S_) * (2 * D_);     // 2*12*64*2048
    __bf16* attn_bf = vt + (size_t)B_ * H_ * HD_ * S_;        // 4096*768

    // 1) qkv = hs @ Wqkv^T (fp32 in, bf16 MFMA; RoPE fused; v -> vt^T)
    gemm_f<1, 2, 1, 1><<<dim3((3 * D_) / 64, (B_ * S_) / 64), 128, 0, stream>>>(
        hs, wqkv, nullptr, qkv, vt, pos, B_ * S_, 3 * D_, D_);

    // 2) banded MFMA attention
    attn_mfma<<<dim3(S_ / 64, H_, B_), 256, 0, stream>>>(qkv, vt, attn_bf);

    // 3) out = attn @ Wo^T (A bf16, B fp32, fp32 out, coalesced epilogue)
    gemm_f<0, 4, 0, 1><<<dim3(D_ / 64, (B_ * S_) / 64), 256, 0, stream>>>(
        attn_bf, wo, out, nullptr, nullptr, nullptr, B_ * S_, D_, D_);
}

// Round 10
// 156.186 us; speedup vs baseline: 1.0914x; 1.0914x over previous
//
#include <hip/hip_runtime.h>
#include <hip/hip_bf16.h>
#include <cmath>

#define B_   2
#define S_   2048
#define D_   768
#define H_   12
#define HD_  64
#define WIN_ 64

typedef __bf16 bf16x8 __attribute__((ext_vector_type(8)));
typedef __bf16 bf16x4 __attribute__((ext_vector_type(4)));
typedef float  f32x4  __attribute__((ext_vector_type(4)));
typedef unsigned int u32;

__device__ __forceinline__ void async_ld16(const void* g, void* l) {
    __builtin_amdgcn_global_load_lds(
        (__attribute__((address_space(1))) void*)(size_t)g,
        (__attribute__((address_space(3))) void*)(u32)(size_t)l,
        16, 0, 0);
}

#define WAIT_VM0   0x0F70   // vmcnt(0), lgkm/exp no-wait
#define WAIT_LGKM0 0xC07F   // lgkmcnt(0), vm/exp no-wait

// ---------------------------------------------------------------------------
// fp32 -> bf16 convert for hs / Wqkv / Wo (one pass)
// ---------------------------------------------------------------------------
#define NHS (B_ * S_ * D_)        // 3145728
#define NWQ (3 * D_ * D_)         // 1769472
#define NWO (D_ * D_)             //  589824

__global__ __launch_bounds__(256) void to_bf16_3(const float* __restrict__ a,
                                                 const float* __restrict__ b,
                                                 const float* __restrict__ c,
                                                 __bf16* __restrict__ oa,
                                                 __bf16* __restrict__ ob,
                                                 __bf16* __restrict__ oc) {
    const int NA = NHS / 4, NB = NWQ / 4;
    int v = blockIdx.x * 256 + threadIdx.x;
    const float* src; __bf16* dst; int idx;
    if (v < NA)           { src = a; dst = oa; idx = v; }
    else if (v < NA + NB) { src = b; dst = ob; idx = v - NA; }
    else                  { src = c; dst = oc; idx = v - NA - NB; }
    float4 x = ((const float4*)src)[idx];
    bf16x4 y = { (__bf16)x.x, (__bf16)x.y, (__bf16)x.z, (__bf16)x.w };
    *(bf16x4*)(dst + (size_t)idx * 4) = y;
}

// ---------------------------------------------------------------------------
// Split-K GEMM (round-8 K-loop, bf16 staging, per-wave vmcnt waits, no
// cross-wave barriers in the loop) + round-9 coalesced LDS-bounce epilogues
// (the 2-B/4-B scatter stores caused write-allocate RMW overfetch).
// C[M,N] = A[M,K] * Bw[N,K]^T, 64x64 tile per block, SPLIT waves split K.
// MODE 0: fp32 C.  MODE 1: fused RoPE -> qkv bf16 (n<1536); v -> vt bf16^T.
// ---------------------------------------------------------------------------
template <int MODE, int SPLIT>
__global__ __launch_bounds__(64 * SPLIT) void gemm_s(const __bf16* __restrict__ A,
                                                     const __bf16* __restrict__ Bw,
                                                     float* __restrict__ C,
                                                     __bf16* __restrict__ qkv,
                                                     __bf16* __restrict__ vt,
                                                     const int* __restrict__ pos,
                                                     int M, int N, int K) {
    __shared__ __attribute__((aligned(16))) char smem[SPLIT * 8192];

    const int tid  = threadIdx.x;
    const int w    = tid >> 6;
    const int lane = tid & 63;
    const int m0 = blockIdx.y * 64;
    const int n0 = blockIdx.x * 64;
    const int fr = lane & 15, fq = lane >> 4;
    const int sw = (fq + (fr >> 1)) & 3;      // swizzled chunk-in-row for frags

    __bf16* As = (__bf16*)(smem + w * 8192);
    __bf16* Bs = As + 2048;

    f32x4 acc[4][4] = {};

    const int nkw = (K / SPLIT) >> 5;         // k-iters per wave
    const int kbase = w * (K / SPLIT);

    for (int ki = 0; ki < nkw; ++ki) {
        const int k0 = kbase + (ki << 5);
        __builtin_amdgcn_s_waitcnt(WAIT_LGKM0);   // prior frag reads retired
        #pragma unroll
        for (int i = 0; i < 4; ++i) {
            const int c = i * 64 + lane;           // LDS chunk index (16B)
            const int row = c >> 2, ccp = c & 3;
            const int cc = (ccp - (row >> 1)) & 3; // source chunk permute
            async_ld16(A  + (size_t)(m0 + row) * K + k0 + cc * 8, As + c * 8);
            async_ld16(Bw + (size_t)(n0 + row) * K + k0 + cc * 8, Bs + c * 8);
        }
        __builtin_amdgcn_s_waitcnt(WAIT_VM0);      // this wave's loads landed

        bf16x8 af[4], bfv[4];
        #pragma unroll
        for (int t = 0; t < 4; ++t) {
            af[t]  = *(const bf16x8*)(As + (t * 16 + fr) * 32 + sw * 8);
            bfv[t] = *(const bf16x8*)(Bs + (t * 16 + fr) * 32 + sw * 8);
        }
        #pragma unroll
        for (int ti = 0; ti < 4; ++ti)
            #pragma unroll
            for (int tj = 0; tj < 4; ++tj)
                acc[ti][tj] = __builtin_amdgcn_mfma_f32_16x16x32_bf16(
                    af[ti], bfv[tj], acc[ti][tj], 0, 0, 0);
    }

    // ---- serial lane-aligned reduction into wave 0 ----
    float* red = (float*)(smem + SPLIT * 8192 - 16384);
    __syncthreads();
    #pragma unroll
    for (int src = 1; src < SPLIT; ++src) {
        if (w == src) {
            #pragma unroll
            for (int ti = 0; ti < 4; ++ti)
                #pragma unroll
                for (int tj = 0; tj < 4; ++tj)
                    *(f32x4*)(red + (ti * 4 + tj) * 256 + lane * 4) = acc[ti][tj];
        }
        __syncthreads();
        if (w == 0) {
            #pragma unroll
            for (int ti = 0; ti < 4; ++ti)
                #pragma unroll
                for (int tj = 0; tj < 4; ++tj)
                    acc[ti][tj] += *(const f32x4*)(red + (ti * 4 + tj) * 256 + lane * 4);
        }
        __syncthreads();
    }
    if (w != 0) return;

    // ---- wave-0 epilogue, coalesced via LDS bounce ----
    if (MODE == 0) {
        float* eL = (float*)smem;                 // [64][65] fp32 (2-way free)
        #pragma unroll
        for (int ti = 0; ti < 4; ++ti)
            #pragma unroll
            for (int tj = 0; tj < 4; ++tj)
                #pragma unroll
                for (int r = 0; r < 4; ++r)
                    eL[(ti * 16 + fq * 4 + r) * 65 + tj * 16 + fr] = acc[ti][tj][r];
        #pragma unroll
        for (int p = 0; p < 16; ++p) {
            const int rc = p * 4 + (lane >> 4), ch = lane & 15;
            f32x4 vv = *(const f32x4*)(eL + rc * 65 + ch * 4);
            *(f32x4*)(C + (size_t)(m0 + rc) * N + n0 + ch * 4) = vv;
        }
    } else if (n0 < 2 * D_) {
        // fused RoPE on fp32 acc, then bf16 coalesced store
        const float invf0 = __powf(10000.0f, -(float)fr * (1.0f / 32.0f));
        const float invf1 = __powf(10000.0f, -(float)(16 + fr) * (1.0f / 32.0f));
        #pragma unroll
        for (int ti = 0; ti < 4; ++ti)
            #pragma unroll
            for (int r = 0; r < 4; ++r) {
                const int row = m0 + ti * 16 + fq * 4 + r;
                const float p = (float)pos[row];
                float s0, c0, s1, c1;
                __sincosf(p * invf0, &s0, &c0);
                __sincosf(p * invf1, &s1, &c1);
                const float x0 = acc[ti][0][r], x1 = acc[ti][2][r];
                acc[ti][0][r] = x0 * c0 - x1 * s0;
                acc[ti][2][r] = x1 * c0 + x0 * s0;
                const float y0 = acc[ti][1][r], y1 = acc[ti][3][r];
                acc[ti][1][r] = y0 * c1 - y1 * s1;
                acc[ti][3][r] = y1 * c1 + y0 * s1;
            }
        __bf16* eL = (__bf16*)smem;               // [64][68] bf16 (2-way free)
        #pragma unroll
        for (int ti = 0; ti < 4; ++ti)
            #pragma unroll
            for (int tj = 0; tj < 4; ++tj)
                #pragma unroll
                for (int r = 0; r < 4; ++r)
                    eL[(ti * 16 + fq * 4 + r) * 68 + tj * 16 + fr] = (__bf16)acc[ti][tj][r];
        #pragma unroll
        for (int p = 0; p < 8; ++p) {
            const int rq = p * 8 + (lane >> 3), ch = lane & 7;
            bf16x8 vv = *(const bf16x8*)(eL + rq * 68 + ch * 8);
            *(bf16x8*)(qkv + (size_t)(m0 + rq) * (2 * D_) + n0 + ch * 8) = vv;
        }
    } else {
        // v -> vt[b][h][d][token], transposed in LDS, coalesced 128-B rows
        const int h = (n0 - 2 * D_) >> 6;
        const int bb = m0 >> 11, t0 = m0 & (S_ - 1);
        __bf16* eL = (__bf16*)smem;               // [64 d][68 tok] bf16
        #pragma unroll
        for (int ti = 0; ti < 4; ++ti)
            #pragma unroll
            for (int tj = 0; tj < 4; ++tj)
                #pragma unroll
                for (int r = 0; r < 4; ++r)
                    eL[(tj * 16 + fr) * 68 + ti * 16 + fq * 4 + r] = (__bf16)acc[ti][tj][r];
        const size_t vb = (size_t)((bb * H_ + h) * HD_) * S_ + t0;
        #pragma unroll
        for (int p = 0; p < 8; ++p) {
            const int d = p * 8 + (lane >> 3), ch = lane & 7;
            bf16x8 vv = *(const bf16x8*)(eL + d * 68 + ch * 8);
            *(bf16x8*)(vt + vb + (size_t)d * S_ + ch * 8) = vv;
        }
    }
}

// ---------------------------------------------------------------------------
// MFMA banded attention.  Block = 64 queries x (head, batch), 4 waves.
// LDS (48 KB): Ks [2][192][32] (24 KB, overlaid by P), Vts [6][64][32] (24 KB).
// Q frags direct from global.  O store bounced through LDS (coalesced 128-B).
// ---------------------------------------------------------------------------
__global__ __launch_bounds__(256) void attn_mfma(const __bf16* __restrict__ qkv,
                                                 const __bf16* __restrict__ vt,
                                                 __bf16* __restrict__ outb) {
    __shared__ __attribute__((aligned(16))) __bf16 smem[24576];  // 48 KB
    __bf16* Ks  = smem;
    __bf16* Vts = smem + 12288;

    const int i0  = blockIdx.x * 64;
    const int h   = blockIdx.y;
    const int b   = blockIdx.z;
    const int tid = threadIdx.x;
    const int w = tid >> 6, lane = tid & 63;
    const int fr = lane & 15, fq = lane >> 4;
    const int wq0 = w * 16;

    #pragma unroll
    for (int i = 0; i < 6; ++i) {
        int c = i * 256 + tid;
        int ks = (i >= 3);
        int rem = c - ks * 768;
        int cc = rem & 3, row = rem >> 2;
        int j = i0 - 64 + row; j = min(max(j, 0), S_ - 1);   // clamped; masked later
        async_ld16(qkv + ((size_t)b * S_ + j) * (2 * D_) + D_ + h * HD_ + ks * 32 + cc * 8,
                   Ks + c * 8);
    }
    const size_t vbase = (size_t)((b * H_ + h) * HD_) * S_;
    #pragma unroll
    for (int i = 0; i < 6; ++i) {
        int c = i * 256 + tid;
        int ks = c >> 8, rem = c & 255, d = rem >> 2, cc = rem & 3;
        int key = i0 - 64 + ks * 32 + cc * 8;
        key = min(max(key, 0), S_ - 8);                      // clamped; masked later
        async_ld16(vt + vbase + (size_t)d * S_ + key, Vts + c * 8);
    }

    const size_t qrow = ((size_t)b * S_ + i0 + wq0 + fr) * (2 * D_) + h * HD_;
    bf16x8 aq[2];
    aq[0] = *(const bf16x8*)(qkv + qrow + fq * 8);
    aq[1] = *(const bf16x8*)(qkv + qrow + 32 + fq * 8);

    __syncthreads();

    f32x4 sc[12] = {};
    #pragma unroll
    for (int nt = 0; nt < 12; ++nt) {
        #pragma unroll
        for (int ks = 0; ks < 2; ++ks) {
            bf16x8 bk = *(const bf16x8*)(Ks + (ks * 192 + nt * 16 + fr) * 32 + fq * 8);
            sc[nt] = __builtin_amdgcn_mfma_f32_16x16x32_bf16(aq[ks], bk, sc[nt], 0, 0, 0);
        }
    }

    float mx[4] = { -1e30f, -1e30f, -1e30f, -1e30f };
    #pragma unroll
    for (int nt = 0; nt < 12; ++nt) {
        const int jr = nt * 16 + fr;
        const int j  = i0 - 64 + jr;
        const bool jv = (j >= 0) && (j < S_);
        #pragma unroll
        for (int r = 0; r < 4; ++r) {
            const int ir = wq0 + fq * 4 + r + 64;
            const int dd = ir - jr;
            const bool v = jv && (dd <= WIN_) && (dd >= -WIN_);
            sc[nt][r] = v ? sc[nt][r] * 0.125f : -1e30f;
            mx[r] = fmaxf(mx[r], sc[nt][r]);
        }
    }
    #pragma unroll
    for (int r = 0; r < 4; ++r)
        #pragma unroll
        for (int off = 1; off < 16; off <<= 1)
            mx[r] = fmaxf(mx[r], __shfl_xor(mx[r], off, 64));

    float sm[4] = { 0.f, 0.f, 0.f, 0.f };
    #pragma unroll
    for (int nt = 0; nt < 12; ++nt)
        #pragma unroll
        for (int r = 0; r < 4; ++r) {
            float e = __expf(sc[nt][r] - mx[r]);
            sc[nt][r] = e;
            sm[r] += e;
        }
    #pragma unroll
    for (int r = 0; r < 4; ++r) {
        #pragma unroll
        for (int off = 1; off < 16; off <<= 1)
            sm[r] += __shfl_xor(sm[r], off, 64);
        sm[r] = 1.0f / sm[r];
    }

    __syncthreads();

    __bf16* Pw = Ks + w * 3072;
    #pragma unroll
    for (int nt = 0; nt < 12; ++nt) {
        const int ks = nt >> 1, kk = (nt & 1) * 16 + fr;
        #pragma unroll
        for (int r = 0; r < 4; ++r)
            Pw[(ks * 16 + fq * 4 + r) * 32 + kk] = (__bf16)(sc[nt][r] * sm[r]);
    }

    f32x4 oacc[4] = {};
    #pragma unroll
    for (int ks = 0; ks < 6; ++ks) {
        bf16x8 ap = *(const bf16x8*)(Pw + (ks * 16 + fr) * 32 + fq * 8);
        #pragma unroll
        for (int nt2 = 0; nt2 < 4; ++nt2) {
            bf16x8 bv = *(const bf16x8*)(Vts + (ks * 64 + nt2 * 16 + fr) * 32 + fq * 8);
            oacc[nt2] = __builtin_amdgcn_mfma_f32_16x16x32_bf16(ap, bv, oacc[nt2], 0, 0, 0);
        }
    }

    // O via per-wave LDS bounce (reuse Pw region) -> coalesced 128-B rows
    #pragma unroll
    for (int nt2 = 0; nt2 < 4; ++nt2)
        #pragma unroll
        for (int r = 0; r < 4; ++r)
            Pw[(fq * 4 + r) * 68 + nt2 * 16 + fr] = (__bf16)oacc[nt2][r];
    #pragma unroll
    for (int p = 0; p < 2; ++p) {
        const int q = p * 8 + (lane >> 3), ch = lane & 7;
        bf16x8 vv = *(const bf16x8*)(Pw + q * 68 + ch * 8);
        *(bf16x8*)(outb + ((size_t)b * S_ + i0 + wq0 + q) * D_ + h * HD_ + ch * 8) = vv;
    }
}

// ---------------------------------------------------------------------------
extern "C" void kernel_launch(void* const* d_in, const int* in_sizes, int n_in,
                              void* d_out, int out_size, void* d_ws, size_t ws_size,
                              hipStream_t stream) {
    const float* hs   = (const float*)d_in[0];
    const float* wqkv = (const float*)d_in[1];
    const float* wo   = (const float*)d_in[2];
    const int*   pos  = (const int*)d_in[4];
    float* out = (float*)d_out;

    __bf16* base    = (__bf16*)d_ws;
    __bf16* hs_bf   = base;                          // 3,145,728
    __bf16* wqkv_bf = hs_bf + NHS;                   // 1,769,472
    __bf16* wo_bf   = wqkv_bf + NWQ;                 //   589,824
    __bf16* qkv     = wo_bf + NWO;                   // 4096*1536
    __bf16* vt      = qkv + (size_t)(B_ * S_) * (2 * D_);   // 2*12*64*2048
    __bf16* attn_bf = vt + (size_t)B_ * H_ * HD_ * S_;      // 4096*768

    // 1) fp32 -> bf16
    to_bf16_3<<<(NHS + NWQ + NWO) / 1024, 256, 0, stream>>>(
        hs, wqkv, wo, hs_bf, wqkv_bf, wo_bf);

    // 2) qkv = hs @ Wqkv^T  (RoPE fused -> qkv bf16; v -> vt transposed)
    gemm_s<1, 2><<<dim3((3 * D_) / 64, (B_ * S_) / 64), 128, 0, stream>>>(
        hs_bf, wqkv_bf, nullptr, qkv, vt, pos, B_ * S_, 3 * D_, D_);

    // 3) banded MFMA attention
    attn_mfma<<<dim3(S_ / 64, H_, B_), 256, 0, stream>>>(qkv, vt, attn_bf);

    // 4) out = attn @ Wo^T (fp32 out, coalesced epilogue)
    gemm_s<0, 4><<<dim3(D_ / 64, (B_ * S_) / 64), 256, 0, stream>>>(
        attn_bf, wo_bf, out, nullptr, nullptr, nullptr, B_ * S_, D_, D_);
}

// Round 11
// 149.860 us; speedup vs baseline: 1.1375x; 1.0422x over previous
//
#include <hip/hip_runtime.h>
#include <hip/hip_bf16.h>
#include <cmath>

#define B_   2
#define S_   2048
#define D_   768
#define H_   12
#define HD_  64
#define WIN_ 64

typedef __bf16 bf16x8 __attribute__((ext_vector_type(8)));
typedef __bf16 bf16x4 __attribute__((ext_vector_type(4)));
typedef float  f32x4  __attribute__((ext_vector_type(4)));
typedef unsigned int u32;

__device__ __forceinline__ void async_ld16(const void* g, void* l) {
    __builtin_amdgcn_global_load_lds(
        (__attribute__((address_space(1))) void*)(size_t)g,
        (__attribute__((address_space(3))) void*)(u32)(size_t)l,
        16, 0, 0);
}

#define WAIT_VM0   0x0F70   // vmcnt(0), lgkm/exp no-wait
#define WAIT_LGKM0 0xC07F   // lgkmcnt(0), vm/exp no-wait

// ---------------------------------------------------------------------------
// fp32 -> bf16 convert for hs / Wqkv / Wo (one pass)
// ---------------------------------------------------------------------------
#define NHS (B_ * S_ * D_)        // 3145728
#define NWQ (3 * D_ * D_)         // 1769472
#define NWO (D_ * D_)             //  589824

__global__ __launch_bounds__(256) void to_bf16_3(const float* __restrict__ a,
                                                 const float* __restrict__ b,
                                                 const float* __restrict__ c,
                                                 __bf16* __restrict__ oa,
                                                 __bf16* __restrict__ ob,
                                                 __bf16* __restrict__ oc) {
    const int NA = NHS / 4, NB = NWQ / 4;
    int v = blockIdx.x * 256 + threadIdx.x;
    const float* src; __bf16* dst; int idx;
    if (v < NA)           { src = a; dst = oa; idx = v; }
    else if (v < NA + NB) { src = b; dst = ob; idx = v - NA; }
    else                  { src = c; dst = oc; idx = v - NA - NB; }
    float4 x = ((const float4*)src)[idx];
    bf16x4 y = { (__bf16)x.x, (__bf16)x.y, (__bf16)x.z, (__bf16)x.w };
    *(bf16x4*)(dst + (size_t)idx * 4) = y;
}

// ---------------------------------------------------------------------------
// Split-K GEMM (round-8 K-loop: bf16 staging, per-wave vmcnt waits, no
// in-loop cross-wave barriers) + coalesced LDS-bounce epilogues.
// NEW (round 11): 1-D grid, m-fastest tile decode (m = id & 63, n = id >> 6).
// Consecutive blocks share the B panel; under round-robin block->XCD
// dispatch each XCD only touches m = xcd (mod 8) A-panels (0.79 MB,
// L2-resident) + streams B once -> panel re-fetch traffic drops ~450 MB
// -> ~40 MB.  Pure index remap; K-loop and epilogues unchanged.
// MODE 0: fp32 C.  MODE 1: fused RoPE -> qkv bf16 (n<1536); v -> vt bf16^T.
// ---------------------------------------------------------------------------
template <int MODE, int SPLIT>
__global__ __launch_bounds__(64 * SPLIT) void gemm_s(const __bf16* __restrict__ A,
                                                     const __bf16* __restrict__ Bw,
                                                     float* __restrict__ C,
                                                     __bf16* __restrict__ qkv,
                                                     __bf16* __restrict__ vt,
                                                     const int* __restrict__ pos,
                                                     int M, int N, int K) {
    __shared__ __attribute__((aligned(16))) char smem[SPLIT * 8192];

    const int tid  = threadIdx.x;
    const int w    = tid >> 6;
    const int lane = tid & 63;
    const int id = blockIdx.x;
    const int m0 = (id & 63) << 6;        // m fastest: B-panel shared by
    const int n0 = (id >> 6) << 6;        // consecutive blocks; A-panels
                                          // partitioned across XCDs by id%8
    const int fr = lane & 15, fq = lane >> 4;
    const int sw = (fq + (fr >> 1)) & 3;  // swizzled chunk-in-row for frags

    __bf16* As = (__bf16*)(smem + w * 8192);
    __bf16* Bs = As + 2048;

    f32x4 acc[4][4] = {};

    const int nkw = (K / SPLIT) >> 5;     // k-iters per wave
    const int kbase = w * (K / SPLIT);

    for (int ki = 0; ki < nkw; ++ki) {
        const int k0 = kbase + (ki << 5);
        __builtin_amdgcn_s_waitcnt(WAIT_LGKM0);   // prior frag reads retired
        #pragma unroll
        for (int i = 0; i < 4; ++i) {
            const int c = i * 64 + lane;           // LDS chunk index (16B)
            const int row = c >> 2, ccp = c & 3;
            const int cc = (ccp - (row >> 1)) & 3; // source chunk permute
            async_ld16(A  + (size_t)(m0 + row) * K + k0 + cc * 8, As + c * 8);
            async_ld16(Bw + (size_t)(n0 + row) * K + k0 + cc * 8, Bs + c * 8);
        }
        __builtin_amdgcn_s_waitcnt(WAIT_VM0);      // this wave's loads landed

        bf16x8 af[4], bfv[4];
        #pragma unroll
        for (int t = 0; t < 4; ++t) {
            af[t]  = *(const bf16x8*)(As + (t * 16 + fr) * 32 + sw * 8);
            bfv[t] = *(const bf16x8*)(Bs + (t * 16 + fr) * 32 + sw * 8);
        }
        #pragma unroll
        for (int ti = 0; ti < 4; ++ti)
            #pragma unroll
            for (int tj = 0; tj < 4; ++tj)
                acc[ti][tj] = __builtin_amdgcn_mfma_f32_16x16x32_bf16(
                    af[ti], bfv[tj], acc[ti][tj], 0, 0, 0);
    }

    // ---- serial lane-aligned reduction into wave 0 ----
    float* red = (float*)(smem + SPLIT * 8192 - 16384);
    __syncthreads();
    #pragma unroll
    for (int src = 1; src < SPLIT; ++src) {
        if (w == src) {
            #pragma unroll
            for (int ti = 0; ti < 4; ++ti)
                #pragma unroll
                for (int tj = 0; tj < 4; ++tj)
                    *(f32x4*)(red + (ti * 4 + tj) * 256 + lane * 4) = acc[ti][tj];
        }
        __syncthreads();
        if (w == 0) {
            #pragma unroll
            for (int ti = 0; ti < 4; ++ti)
                #pragma unroll
                for (int tj = 0; tj < 4; ++tj)
                    acc[ti][tj] += *(const f32x4*)(red + (ti * 4 + tj) * 256 + lane * 4);
        }
        __syncthreads();
    }
    if (w != 0) return;

    // ---- wave-0 epilogue, coalesced via LDS bounce ----
    if (MODE == 0) {
        float* eL = (float*)smem;                 // [64][65] fp32 (2-way free)
        #pragma unroll
        for (int ti = 0; ti < 4; ++ti)
            #pragma unroll
            for (int tj = 0; tj < 4; ++tj)
                #pragma unroll
                for (int r = 0; r < 4; ++r)
                    eL[(ti * 16 + fq * 4 + r) * 65 + tj * 16 + fr] = acc[ti][tj][r];
        #pragma unroll
        for (int p = 0; p < 16; ++p) {
            const int rc = p * 4 + (lane >> 4), ch = lane & 15;
            f32x4 vv = *(const f32x4*)(eL + rc * 65 + ch * 4);
            *(f32x4*)(C + (size_t)(m0 + rc) * N + n0 + ch * 4) = vv;
        }
    } else if (n0 < 2 * D_) {
        // fused RoPE on fp32 acc, then bf16 coalesced store
        const float invf0 = __powf(10000.0f, -(float)fr * (1.0f / 32.0f));
        const float invf1 = __powf(10000.0f, -(float)(16 + fr) * (1.0f / 32.0f));
        #pragma unroll
        for (int ti = 0; ti < 4; ++ti)
            #pragma unroll
            for (int r = 0; r < 4; ++r) {
                const int row = m0 + ti * 16 + fq * 4 + r;
                const float p = (float)pos[row];
                float s0, c0, s1, c1;
                __sincosf(p * invf0, &s0, &c0);
                __sincosf(p * invf1, &s1, &c1);
                const float x0 = acc[ti][0][r], x1 = acc[ti][2][r];
                acc[ti][0][r] = x0 * c0 - x1 * s0;
                acc[ti][2][r] = x1 * c0 + x0 * s0;
                const float y0 = acc[ti][1][r], y1 = acc[ti][3][r];
                acc[ti][1][r] = y0 * c1 - y1 * s1;
                acc[ti][3][r] = y1 * c1 + y0 * s1;
            }
        __bf16* eL = (__bf16*)smem;               // [64][68] bf16 (2-way free)
        #pragma unroll
        for (int ti = 0; ti < 4; ++ti)
            #pragma unroll
            for (int tj = 0; tj < 4; ++tj)
                #pragma unroll
                for (int r = 0; r < 4; ++r)
                    eL[(ti * 16 + fq * 4 + r) * 68 + tj * 16 + fr] = (__bf16)acc[ti][tj][r];
        #pragma unroll
        for (int p = 0; p < 8; ++p) {
            const int rq = p * 8 + (lane >> 3), ch = lane & 7;
            bf16x8 vv = *(const bf16x8*)(eL + rq * 68 + ch * 8);
            *(bf16x8*)(qkv + (size_t)(m0 + rq) * (2 * D_) + n0 + ch * 8) = vv;
        }
    } else {
        // v -> vt[b][h][d][token], transposed in LDS, coalesced 128-B rows
        const int h = (n0 - 2 * D_) >> 6;
        const int bb = m0 >> 11, t0 = m0 & (S_ - 1);
        __bf16* eL = (__bf16*)smem;               // [64 d][68 tok] bf16
        #pragma unroll
        for (int ti = 0; ti < 4; ++ti)
            #pragma unroll
            for (int tj = 0; tj < 4; ++tj)
                #pragma unroll
                for (int r = 0; r < 4; ++r)
                    eL[(tj * 16 + fr) * 68 + ti * 16 + fq * 4 + r] = (__bf16)acc[ti][tj][r];
        const size_t vb = (size_t)((bb * H_ + h) * HD_) * S_ + t0;
        #pragma unroll
        for (int p = 0; p < 8; ++p) {
            const int d = p * 8 + (lane >> 3), ch = lane & 7;
            bf16x8 vv = *(const bf16x8*)(eL + d * 68 + ch * 8);
            *(bf16x8*)(vt + vb + (size_t)d * S_ + ch * 8) = vv;
        }
    }
}

// ---------------------------------------------------------------------------
// MFMA banded attention.  Block = 64 queries x (head, batch), 4 waves.
// LDS (48 KB): Ks [2][192][32] (24 KB, overlaid by P), Vts [6][64][32] (24 KB).
// Q frags direct from global.  O store bounced through LDS (coalesced 128-B).
// ---------------------------------------------------------------------------
__global__ __launch_bounds__(256) void attn_mfma(const __bf16* __restrict__ qkv,
                                                 const __bf16* __restrict__ vt,
                                                 __bf16* __restrict__ outb) {
    __shared__ __attribute__((aligned(16))) __bf16 smem[24576];  // 48 KB
    __bf16* Ks  = smem;
    __bf16* Vts = smem + 12288;

    const int i0  = blockIdx.x * 64;
    const int h   = blockIdx.y;
    const int b   = blockIdx.z;
    const int tid = threadIdx.x;
    const int w = tid >> 6, lane = tid & 63;
    const int fr = lane & 15, fq = lane >> 4;
    const int wq0 = w * 16;

    #pragma unroll
    for (int i = 0; i < 6; ++i) {
        int c = i * 256 + tid;
        int ks = (i >= 3);
        int rem = c - ks * 768;
        int cc = rem & 3, row = rem >> 2;
        int j = i0 - 64 + row; j = min(max(j, 0), S_ - 1);   // clamped; masked later
        async_ld16(qkv + ((size_t)b * S_ + j) * (2 * D_) + D_ + h * HD_ + ks * 32 + cc * 8,
                   Ks + c * 8);
    }
    const size_t vbase = (size_t)((b * H_ + h) * HD_) * S_;
    #pragma unroll
    for (int i = 0; i < 6; ++i) {
        int c = i * 256 + tid;
        int ks = c >> 8, rem = c & 255, d = rem >> 2, cc = rem & 3;
        int key = i0 - 64 + ks * 32 + cc * 8;
        key = min(max(key, 0), S_ - 8);                      // clamped; masked later
        async_ld16(vt + vbase + (size_t)d * S_ + key, Vts + c * 8);
    }

    const size_t qrow = ((size_t)b * S_ + i0 + wq0 + fr) * (2 * D_) + h * HD_;
    bf16x8 aq[2];
    aq[0] = *(const bf16x8*)(qkv + qrow + fq * 8);
    aq[1] = *(const bf16x8*)(qkv + qrow + 32 + fq * 8);

    __syncthreads();

    f32x4 sc[12] = {};
    #pragma unroll
    for (int nt = 0; nt < 12; ++nt) {
        #pragma unroll
        for (int ks = 0; ks < 2; ++ks) {
            bf16x8 bk = *(const bf16x8*)(Ks + (ks * 192 + nt * 16 + fr) * 32 + fq * 8);
            sc[nt] = __builtin_amdgcn_mfma_f32_16x16x32_bf16(aq[ks], bk, sc[nt], 0, 0, 0);
        }
    }

    float mx[4] = { -1e30f, -1e30f, -1e30f, -1e30f };
    #pragma unroll
    for (int nt = 0; nt < 12; ++nt) {
        const int jr = nt * 16 + fr;
        const int j  = i0 - 64 + jr;
        const bool jv = (j >= 0) && (j < S_);
        #pragma unroll
        for (int r = 0; r < 4; ++r) {
            const int ir = wq0 + fq * 4 + r + 64;
            const int dd = ir - jr;
            const bool v = jv && (dd <= WIN_) && (dd >= -WIN_);
            sc[nt][r] = v ? sc[nt][r] * 0.125f : -1e30f;
            mx[r] = fmaxf(mx[r], sc[nt][r]);
        }
    }
    #pragma unroll
    for (int r = 0; r < 4; ++r)
        #pragma unroll
        for (int off = 1; off < 16; off <<= 1)
            mx[r] = fmaxf(mx[r], __shfl_xor(mx[r], off, 64));

    float sm[4] = { 0.f, 0.f, 0.f, 0.f };
    #pragma unroll
    for (int nt = 0; nt < 12; ++nt)
        #pragma unroll
        for (int r = 0; r < 4; ++r) {
            float e = __expf(sc[nt][r] - mx[r]);
            sc[nt][r] = e;
            sm[r] += e;
        }
    #pragma unroll
    for (int r = 0; r < 4; ++r) {
        #pragma unroll
        for (int off = 1; off < 16; off <<= 1)
            sm[r] += __shfl_xor(sm[r], off, 64);
        sm[r] = 1.0f / sm[r];
    }

    __syncthreads();

    __bf16* Pw = Ks + w * 3072;
    #pragma unroll
    for (int nt = 0; nt < 12; ++nt) {
        const int ks = nt >> 1, kk = (nt & 1) * 16 + fr;
        #pragma unroll
        for (int r = 0; r < 4; ++r)
            Pw[(ks * 16 + fq * 4 + r) * 32 + kk] = (__bf16)(sc[nt][r] * sm[r]);
    }

    f32x4 oacc[4] = {};
    #pragma unroll
    for (int ks = 0; ks < 6; ++ks) {
        bf16x8 ap = *(const bf16x8*)(Pw + (ks * 16 + fr) * 32 + fq * 8);
        #pragma unroll
        for (int nt2 = 0; nt2 < 4; ++nt2) {
            bf16x8 bv = *(const bf16x8*)(Vts + (ks * 64 + nt2 * 16 + fr) * 32 + fq * 8);
            oacc[nt2] = __builtin_amdgcn_mfma_f32_16x16x32_bf16(ap, bv, oacc[nt2], 0, 0, 0);
        }
    }

    // O via per-wave LDS bounce (reuse Pw region) -> coalesced 128-B rows
    #pragma unroll
    for (int nt2 = 0; nt2 < 4; ++nt2)
        #pragma unroll
        for (int r = 0; r < 4; ++r)
            Pw[(fq * 4 + r) * 68 + nt2 * 16 + fr] = (__bf16)oacc[nt2][r];
    #pragma unroll
    for (int p = 0; p < 2; ++p) {
        const int q = p * 8 + (lane >> 3), ch = lane & 7;
        bf16x8 vv = *(const bf16x8*)(Pw + q * 68 + ch * 8);
        *(bf16x8*)(outb + ((size_t)b * S_ + i0 + wq0 + q) * D_ + h * HD_ + ch * 8) = vv;
    }
}

// ---------------------------------------------------------------------------
extern "C" void kernel_launch(void* const* d_in, const int* in_sizes, int n_in,
                              void* d_out, int out_size, void* d_ws, size_t ws_size,
                              hipStream_t stream) {
    const float* hs   = (const float*)d_in[0];
    const float* wqkv = (const float*)d_in[1];
    const float* wo   = (const float*)d_in[2];
    const int*   pos  = (const int*)d_in[4];
    float* out = (float*)d_out;

    __bf16* base    = (__bf16*)d_ws;
    __bf16* hs_bf   = base;                          // 3,145,728
    __bf16* wqkv_bf = hs_bf + NHS;                   // 1,769,472
    __bf16* wo_bf   = wqkv_bf + NWQ;                 //   589,824
    __bf16* qkv     = wo_bf + NWO;                   // 4096*1536
    __bf16* vt      = qkv + (size_t)(B_ * S_) * (2 * D_);   // 2*12*64*2048
    __bf16* attn_bf = vt + (size_t)B_ * H_ * HD_ * S_;      // 4096*768

    // 1) fp32 -> bf16
    to_bf16_3<<<(NHS + NWQ + NWO) / 1024, 256, 0, stream>>>(
        hs, wqkv, wo, hs_bf, wqkv_bf, wo_bf);

    // 2) qkv = hs @ Wqkv^T  (RoPE fused -> qkv bf16; v -> vt transposed)
    //    1-D grid, m-fastest decode (XCD panel partitioning)
    gemm_s<1, 2><<<dim3(64 * (3 * D_ / 64)), 128, 0, stream>>>(
        hs_bf, wqkv_bf, nullptr, qkv, vt, pos, B_ * S_, 3 * D_, D_);

    // 3) banded MFMA attention
    attn_mfma<<<dim3(S_ / 64, H_, B_), 256, 0, stream>>>(qkv, vt, attn_bf);

    // 4) out = attn @ Wo^T (fp32 out, coalesced epilogue)
    gemm_s<0, 4><<<dim3(64 * (D_ / 64)), 256, 0, stream>>>(
        attn_bf, wo_bf, out, nullptr, nullptr, nullptr, B_ * S_, D_, D_);
}